// Round 1
// 837.059 us; speedup vs baseline: 1.2882x; 1.2882x over previous
//
#include <hip/hip_runtime.h>
#include <hip/hip_bf16.h>
#include <stdint.h>

#define GLOBAL_AS __attribute__((address_space(1)))
#define LDS_AS    __attribute__((address_space(3)))

typedef __attribute__((ext_vector_type(8))) short  short8;   // 8 x bf16 bits (4 VGPRs)
typedef __attribute__((ext_vector_type(4))) float  floatx4;  // MFMA C/D

constexpr int BATCH = 8192;
constexpr int OUT   = 2048;
constexpr int KDIM  = 4096;   // INPUT+OUTPUT

constexpr size_t IH_ELEMS = (size_t)BATCH * KDIM;      // 33,554,432
constexpr size_t W_ELEMS  = (size_t)4 * OUT * KDIM;    // 33,554,432

// ---- 256x256x64 8-phase GEMM geometry ----
constexpr int TBM = 256;           // batch rows / block
constexpr int TBN = 256;           // = 4 gates x 64 outputs / block
constexpr int TBK = 64;            // k per K-tile
constexpr int TNT = KDIM / TBK;    // 64 K-tiles

__device__ __forceinline__ unsigned int cvt2(float a, float b) {
    union { __hip_bfloat162 h; unsigned int u; } v;
    v.h = __float22bfloat162_rn(make_float2(a, b));   // v_cvt_pk_bf16_f32
    return v.u;
}
__device__ __forceinline__ float sigmoidf_(float x) {
    return 1.0f / (1.0f + __expf(-x));
}
__device__ __forceinline__ void stage16(const unsigned short* g, unsigned short* l) {
    __builtin_amdgcn_global_load_lds((const GLOBAL_AS uint32_t*)g,
                                     (LDS_AS uint32_t*)l, 16, 0, 0);
}
__device__ __forceinline__ floatx4 mfma16(short8 a, short8 b, floatx4 c) {
    return __builtin_amdgcn_mfma_f32_16x16x32_bf16(a, b, c, 0, 0, 0);
}

// ---------------- phase 1: f32 -> bf16 conversion into workspace ----------------
// One kernel for ihb [8192][4096] and Wb [4*2048][4096] (gate-major).

__global__ __launch_bounds__(256)
void cvt_all(const float* __restrict__ I, const float* __restrict__ H,
             const float* __restrict__ W1, const float* __restrict__ W2,
             const float* __restrict__ W3, const float* __restrict__ W4,
             unsigned short* __restrict__ dst)
{
    const size_t t = (size_t)blockIdx.x * 256 + threadIdx.x;   // 8,388,608 threads
    const size_t e = t * 8;
    const float* s;
    if (e < IH_ELEMS) {
        const int b = (int)(e >> 12);          // row (4096 elems/row)
        const int k = (int)(e & 4095);
        s = (k < 2048) ? (I + (size_t)b * 2048 + k)
                       : (H + (size_t)b * 2048 + (k - 2048));
    } else {
        const size_t e2 = e - IH_ELEMS;
        const int g = (int)(e2 >> 23);         // / (2048*4096)
        const size_t rem = e2 & 8388607u;
        const float* Wg = (g == 0) ? W1 : (g == 1) ? W2 : (g == 2) ? W3 : W4;
        s = Wg + rem;
    }
    const float4 x = ((const float4*)s)[0];
    const float4 y = ((const float4*)s)[1];
    uint4 o;
    o.x = cvt2(x.x, x.y); o.y = cvt2(x.z, x.w);
    o.z = cvt2(y.x, y.y); o.w = cvt2(y.z, y.w);
    *(uint4*)(dst + e) = o;
}

// ---------------- phase 2: 256^2 8-phase bf16 GEMM + fused LSTM epilogue -------
//
// Schedule (per K-tile t, buffer buf=t&1; 4 phases = 4 C-quadrants (mh,nh)):
//   phase 0 (mh0,nh0): ds_read A-mh0 (8) + B-nh0 (4) | stage A0(t+1) -> buf^1
//   phase 1 (mh0,nh1): ds_read B-nh1 (4)             | stage A1(t+1) -> buf^1
//   phase 2 (mh1,nh0): ds_read A-mh1 (8)             | stage B0(t+2) -> buf
//   phase 3 (mh1,nh1): (no reads)                    | stage B1(t+2) -> buf
// Each phase: reads+stage ; s_barrier ; lgkmcnt(0)+sched_barrier ; setprio(1) ;
// 16 MFMA ; setprio(0) ; [phase3: vmcnt(4)] ; s_barrier.  NO __syncthreads.
// Race-freedom: B-halves staged into the live buffer only at phases 2/3, i.e.
// after the barrier following the last B-read (phase 1). A-halves go to the
// other buffer. vmcnt(4) at tile end guarantees tile t+1 fully landed (2
// half-tiles = 4 loads/wave still in flight: B0/B1 of t+2).
// LDS: [buf][A0|A1|B0|B1] 16KB regions; chunk (row,kc) at slot kc^(row&7)
// (source pre-swizzled; global_load_lds dest stays linear).

__global__ __launch_bounds__(512, 2)
void lstm_gemm_8ph(const unsigned short* __restrict__ ihb,
                   const unsigned short* __restrict__ Wb,
                   const float* __restrict__ C,
                   const float* __restrict__ B1, const float* __restrict__ B2,
                   const float* __restrict__ B3, const float* __restrict__ B4,
                   float* __restrict__ Outp)
{
    __shared__ unsigned short smem[65536];    // 128 KiB

    const int tid  = threadIdx.x;
    const int w    = tid >> 6;        // wave 0..7
    const int lane = tid & 63;
    const int col  = lane & 15;
    const int q    = lane >> 4;
    const int wr   = w >> 2;          // 0..1 : M half (128 rows each)
    const int wc   = w & 3;           // 0..3 : 16-wide o-slice

    // bijective XCD swizzle (1024 blocks, 8 XCDs -> 128 contiguous each)
    const int bid = blockIdx.x;
    const int swz = (bid & 7) * 128 + (bid >> 3);
    const int bx  = swz & 31;         // N tile: o0 = bx*64
    const int by  = swz >> 5;         // M tile
    const int bm0 = by * TBM;
    const int o0  = bx * 64;

    // ---- per-thread staging sources (pre-swizzled: slot s holds kc = s^(r&7))
    const unsigned short* srcA[2];
    const unsigned short* srcB[2];
    #pragma unroll
    for (int j = 0; j < 2; ++j) {
        const int c  = (w * 2 + j) * 64 + lane;   // chunk id in 16KB half-tile
        const int r  = c >> 3;                    // row-in-region 0..127
        const int s  = c & 7;                     // 16B slot
        const int kc = s ^ (r & 7);               // un-swizzle: source k-chunk
        srcA[j] = ihb + (size_t)(bm0 + r) * KDIM + kc * 8;
        // B-tile col ci=r (region B0): gate-interleaved so each wave sees all 4
        const int g  = (r >> 4) & 3;
        const int oo = o0 + (r >> 6) * 16 + (r & 15);
        srcB[j] = Wb + (size_t)(g * OUT + oo) * KDIM + kc * 8;
    }
    const int sliceA = w * 1024;      // this wave's j=0 slice (ushort units)

    // ---- fragment read bases ----
    const int c7    = col & 7;
    const int slot0 = ((0 + q) ^ c7) * 8;   // ks=0  (kc = ks*4+q)
    const int slot1 = ((4 + q) ^ c7) * 8;   // ks=1
    const int aBase = wr * 8192 + col * 64;
    const int bBase = 16384 + (wc >> 1) * 8192 + ((wc & 1) * 64 + col) * 64;

    floatx4 acc[8][4];                // [m-frag][gate]
    #pragma unroll
    for (int i = 0; i < 8; ++i)
        #pragma unroll
        for (int j = 0; j < 4; ++j)
            acc[i][j] = (floatx4){0.f, 0.f, 0.f, 0.f};

    // ---- prologue: stage tile0 fully + tile1 B-halves; then vmcnt(4) ----
    stage16(srcA[0],                  &smem[0     + sliceA]);
    stage16(srcA[1],                  &smem[0     + sliceA + 512]);
    stage16(srcA[0] + 128 * KDIM,     &smem[8192  + sliceA]);
    stage16(srcA[1] + 128 * KDIM,     &smem[8192  + sliceA + 512]);
    stage16(srcB[0],                  &smem[16384 + sliceA]);
    stage16(srcB[1],                  &smem[16384 + sliceA + 512]);
    stage16(srcB[0] + 32 * KDIM,      &smem[24576 + sliceA]);
    stage16(srcB[1] + 32 * KDIM,      &smem[24576 + sliceA + 512]);
    stage16(srcB[0] + TBK,            &smem[32768 + 16384 + sliceA]);
    stage16(srcB[1] + TBK,            &smem[32768 + 16384 + sliceA + 512]);
    stage16(srcB[0] + 32 * KDIM + TBK, &smem[32768 + 24576 + sliceA]);
    stage16(srcB[1] + 32 * KDIM + TBK, &smem[32768 + 24576 + sliceA + 512]);
    asm volatile("s_waitcnt vmcnt(4)" ::: "memory");
    __builtin_amdgcn_s_barrier();

    short8 Af[4][2];       // current mh: 4 m-frags x 2 k-slices
    short8 Bf[2][2][2];    // [nh][tn'][ks], held across whole K-tile

    for (int t = 0; t < TNT; ++t) {
        const int buf = t & 1;
        const unsigned short* Ab = smem + buf * 32768 + aBase;
        const unsigned short* Bb = smem + buf * 32768 + bBase;
        unsigned short* stA = smem + (buf ^ 1) * 32768;   // A(t+1) -> other buf
        unsigned short* stB = smem + buf * 32768;         // B(t+2) -> this buf
        const int kA = ((t + 1) < TNT ? (t + 1) : TNT - 1) * TBK;  // clamp keeps
        const int kB = ((t + 2) < TNT ? (t + 2) : TNT - 1) * TBK;  // vmcnt uniform

        // ---------------- phase 0 : (mh=0, nh=0) ----------------
        #pragma unroll
        for (int tm = 0; tm < 4; ++tm) {
            Af[tm][0] = *(const short8*)(Ab + tm * 1024 + slot0);
            Af[tm][1] = *(const short8*)(Ab + tm * 1024 + slot1);
        }
        #pragma unroll
        for (int tn = 0; tn < 2; ++tn) {
            Bf[0][tn][0] = *(const short8*)(Bb + tn * 1024 + slot0);
            Bf[0][tn][1] = *(const short8*)(Bb + tn * 1024 + slot1);
        }
        stage16(srcA[0] + kA, stA + 0 + sliceA);
        stage16(srcA[1] + kA, stA + 0 + sliceA + 512);
        __builtin_amdgcn_s_barrier();
        asm volatile("s_waitcnt lgkmcnt(0)" ::: "memory");
        __builtin_amdgcn_sched_barrier(0);
        __builtin_amdgcn_s_setprio(1);
        #pragma unroll
        for (int tm = 0; tm < 4; ++tm)
            #pragma unroll
            for (int tn = 0; tn < 2; ++tn) {
                acc[tm][tn] = mfma16(Af[tm][0], Bf[0][tn][0], acc[tm][tn]);
                acc[tm][tn] = mfma16(Af[tm][1], Bf[0][tn][1], acc[tm][tn]);
            }
        __builtin_amdgcn_s_setprio(0);
        __builtin_amdgcn_s_barrier();

        // ---------------- phase 1 : (mh=0, nh=1) ----------------
        #pragma unroll
        for (int tn = 0; tn < 2; ++tn) {
            Bf[1][tn][0] = *(const short8*)(Bb + 2048 + tn * 1024 + slot0);
            Bf[1][tn][1] = *(const short8*)(Bb + 2048 + tn * 1024 + slot1);
        }
        stage16(srcA[0] + 128 * KDIM + kA, stA + 8192 + sliceA);
        stage16(srcA[1] + 128 * KDIM + kA, stA + 8192 + sliceA + 512);
        __builtin_amdgcn_s_barrier();
        asm volatile("s_waitcnt lgkmcnt(0)" ::: "memory");
        __builtin_amdgcn_sched_barrier(0);
        __builtin_amdgcn_s_setprio(1);
        #pragma unroll
        for (int tm = 0; tm < 4; ++tm)
            #pragma unroll
            for (int tn = 0; tn < 2; ++tn) {
                acc[tm][2 + tn] = mfma16(Af[tm][0], Bf[1][tn][0], acc[tm][2 + tn]);
                acc[tm][2 + tn] = mfma16(Af[tm][1], Bf[1][tn][1], acc[tm][2 + tn]);
            }
        __builtin_amdgcn_s_setprio(0);
        __builtin_amdgcn_s_barrier();

        // ---------------- phase 2 : (mh=1, nh=0) ----------------
        #pragma unroll
        for (int tm = 0; tm < 4; ++tm) {
            Af[tm][0] = *(const short8*)(Ab + 4096 + tm * 1024 + slot0);
            Af[tm][1] = *(const short8*)(Ab + 4096 + tm * 1024 + slot1);
        }
        stage16(srcB[0] + kB, stB + 16384 + sliceA);
        stage16(srcB[1] + kB, stB + 16384 + sliceA + 512);
        __builtin_amdgcn_s_barrier();
        asm volatile("s_waitcnt lgkmcnt(0)" ::: "memory");
        __builtin_amdgcn_sched_barrier(0);
        __builtin_amdgcn_s_setprio(1);
        #pragma unroll
        for (int tm = 0; tm < 4; ++tm)
            #pragma unroll
            for (int tn = 0; tn < 2; ++tn) {
                acc[4 + tm][tn] = mfma16(Af[tm][0], Bf[0][tn][0], acc[4 + tm][tn]);
                acc[4 + tm][tn] = mfma16(Af[tm][1], Bf[0][tn][1], acc[4 + tm][tn]);
            }
        __builtin_amdgcn_s_setprio(0);
        __builtin_amdgcn_s_barrier();

        // ---------------- phase 3 : (mh=1, nh=1) ----------------
        stage16(srcB[0] + 32 * KDIM + kB, stB + 24576 + sliceA);
        stage16(srcB[1] + 32 * KDIM + kB, stB + 24576 + sliceA + 512);
        __builtin_amdgcn_s_barrier();
        asm volatile("s_waitcnt lgkmcnt(0)" ::: "memory");
        __builtin_amdgcn_sched_barrier(0);
        __builtin_amdgcn_s_setprio(1);
        #pragma unroll
        for (int tm = 0; tm < 4; ++tm)
            #pragma unroll
            for (int tn = 0; tn < 2; ++tn) {
                acc[4 + tm][2 + tn] = mfma16(Af[tm][0], Bf[1][tn][0], acc[4 + tm][2 + tn]);
                acc[4 + tm][2 + tn] = mfma16(Af[tm][1], Bf[1][tn][1], acc[4 + tm][2 + tn]);
            }
        __builtin_amdgcn_s_setprio(0);
        asm volatile("s_waitcnt vmcnt(4)" ::: "memory");   // tile t+1 landed
        __builtin_amdgcn_s_barrier();
    }

    // ---- fused LSTM epilogue, in-register ----
    // thread (col,q), wave (wr,wc): o = o0 + wc*16 + col (fixed);
    // b = bm0 + wr*128 + tm*16 + q*4 + r; acc[tm][gate][r].
    const int o = o0 + wc * 16 + col;
    float bias[4];
    bias[0] = B1[o]; bias[1] = B2[o]; bias[2] = B3[o]; bias[3] = B4[o];

    const size_t HALF = (size_t)BATCH * OUT;
    #pragma unroll
    for (int tm = 0; tm < 8; ++tm) {
        #pragma unroll
        for (int r = 0; r < 4; ++r) {
            const int b = bm0 + wr * 128 + tm * 16 + q * 4 + r;
            const size_t idx = (size_t)b * OUT + o;
            const float cv = C[idx];
            const float o1 = sigmoidf_(acc[tm][0][r] + bias[0]);
            const float o2 = sigmoidf_(acc[tm][1][r] + bias[1]);
            const float o3 = tanhf    (acc[tm][2][r] + bias[2]);
            const float o4 = sigmoidf_(acc[tm][3][r] + bias[3]);
            Outp[idx]        = tanhf(cv) * o4;     // new_h (OLD cell state)
            Outp[HALF + idx] = cv * o1 + o2 * o3;  // new_c
        }
    }
}

// ---------------- fallback: single fused kernel, inline f32->bf16 ----------------

constexpr int FBM = 128;
constexpr int FBO = 32;
constexpr int FBK = 32;

__global__ __launch_bounds__(256)
void lstm_fused_f32(const float* __restrict__ I, const float* __restrict__ H,
                    const float* __restrict__ C,
                    const float* __restrict__ W1, const float* __restrict__ B1,
                    const float* __restrict__ W2, const float* __restrict__ B2,
                    const float* __restrict__ W3, const float* __restrict__ B3,
                    const float* __restrict__ W4, const float* __restrict__ B4,
                    float* __restrict__ Outp)
{
    __shared__ unsigned short As[FBM * FBK];
    __shared__ unsigned short Bs[4 * FBO * FBK];

    const int tid  = threadIdx.x;
    const int w    = tid >> 6;
    const int lane = tid & 63;
    const int col  = lane & 15;
    const int q    = lane >> 4;

    const int bm0 = blockIdx.y * FBM;
    const int o0  = blockIdx.x * FBO;

    long aoff[2], boff[2];
    const float* wptr[2];
    unsigned short* dstA[2];
    unsigned short* dstB[2];
    #pragma unroll
    for (int j = 0; j < 2; ++j) {
        const int win = w * 2 + j;
        const int c   = win * 64 + lane;
        const int row = c >> 2;
        const int kcs = c & 3;
        const int kc  = kcs ^ ((row >> 1) & 3);
        aoff[j] = (long)(bm0 + row) * (KDIM / 2) + kc * 8;
        const int g = row >> 5;
        const int o = o0 + (row & 31);
        wptr[j] = (g == 0) ? W1 : (g == 1) ? W2 : (g == 2) ? W3 : W4;
        boff[j] = (long)o * KDIM + kc * 8;
        dstA[j] = As + (size_t)c * 8;
        dstB[j] = Bs + (size_t)c * 8;
    }

    int aAddr[2];
    #pragma unroll
    for (int tm = 0; tm < 2; ++tm) {
        const int m = w * 32 + tm * 16 + col;
        aAddr[tm] = (m * 4 + (q ^ ((m >> 1) & 3))) * 8;
    }
    int bAddr[8];
    #pragma unroll
    for (int tn = 0; tn < 8; ++tn) {
        const int n = tn * 16 + col;
        bAddr[tn] = (n * 4 + (q ^ ((n >> 1) & 3))) * 8;
    }

    floatx4 acc[2][8];
    #pragma unroll
    for (int tm = 0; tm < 2; ++tm)
        #pragma unroll
        for (int tn = 0; tn < 8; ++tn)
            acc[tm][tn] = (floatx4){0.f, 0.f, 0.f, 0.f};

    for (int k0 = 0; k0 < KDIM; k0 += FBK) {
        #pragma unroll
        for (int j = 0; j < 2; ++j) {
            const float* ab = (k0 < KDIM / 2) ? (I + k0) : (H + (k0 - KDIM / 2));
            const float* sa = ab + aoff[j];
            const float* sb = wptr[j] + boff[j] + k0;
            const float4 a0 = ((const float4*)sa)[0];
            const float4 a1 = ((const float4*)sa)[1];
            const float4 b0 = ((const float4*)sb)[0];
            const float4 b1 = ((const float4*)sb)[1];
            uint4 va, vb;
            va.x = cvt2(a0.x, a0.y); va.y = cvt2(a0.z, a0.w);
            va.z = cvt2(a1.x, a1.y); va.w = cvt2(a1.z, a1.w);
            vb.x = cvt2(b0.x, b0.y); vb.y = cvt2(b0.z, b0.w);
            vb.z = cvt2(b1.x, b1.y); vb.w = cvt2(b1.z, b1.w);
            *(uint4*)dstA[j] = va;
            *(uint4*)dstB[j] = vb;
        }
        __syncthreads();

        const short8 a0 = *(const short8*)(As + aAddr[0]);
        const short8 a1 = *(const short8*)(As + aAddr[1]);
        #pragma unroll
        for (int tn = 0; tn < 8; ++tn) {
            const short8 b = *(const short8*)(Bs + bAddr[tn]);
            acc[0][tn] = __builtin_amdgcn_mfma_f32_16x16x32_bf16(a0, b, acc[0][tn], 0, 0, 0);
            acc[1][tn] = __builtin_amdgcn_mfma_f32_16x16x32_bf16(a1, b, acc[1][tn], 0, 0, 0);
        }
        __syncthreads();
    }

    float bias[2][4];
    #pragma unroll
    for (int obit = 0; obit < 2; ++obit) {
        const int o = o0 + obit * 16 + col;
        bias[obit][0] = B1[o]; bias[obit][1] = B2[o];
        bias[obit][2] = B3[o]; bias[obit][3] = B4[o];
    }

    const size_t HALF = (size_t)BATCH * OUT;
    #pragma unroll
    for (int tm = 0; tm < 2; ++tm) {
        #pragma unroll
        for (int r = 0; r < 4; ++r) {
            const int b = bm0 + w * 32 + tm * 16 + q * 4 + r;
            #pragma unroll
            for (int obit = 0; obit < 2; ++obit) {
                const int o = o0 + obit * 16 + col;
                const size_t idx = (size_t)b * OUT + o;
                const float cv = C[idx];
                const float o1 = sigmoidf_(acc[tm][0 + obit][r] + bias[obit][0]);
                const float o2 = sigmoidf_(acc[tm][2 + obit][r] + bias[obit][1]);
                const float o3 = tanhf   (acc[tm][4 + obit][r] + bias[obit][2]);
                const float o4 = sigmoidf_(acc[tm][6 + obit][r] + bias[obit][3]);
                Outp[idx]        = tanhf(cv) * o4;
                Outp[HALF + idx] = cv * o1 + o2 * o3;
            }
        }
    }
}

extern "C" void kernel_launch(void* const* d_in, const int* in_sizes, int n_in,
                              void* d_out, int out_size, void* d_ws, size_t ws_size,
                              hipStream_t stream) {
    const float* I  = (const float*)d_in[0];
    const float* H  = (const float*)d_in[1];
    const float* C  = (const float*)d_in[2];
    const float* W1 = (const float*)d_in[3];
    const float* B1 = (const float*)d_in[4];
    const float* W2 = (const float*)d_in[5];
    const float* B2 = (const float*)d_in[6];
    const float* W3 = (const float*)d_in[7];
    const float* B3 = (const float*)d_in[8];
    const float* W4 = (const float*)d_in[9];
    const float* B4 = (const float*)d_in[10];
    float* Outp = (float*)d_out;

    const size_t need = (IH_ELEMS + W_ELEMS) * 2;        // 128 MiB bf16

    if (ws_size >= need) {
        unsigned short* ihb = (unsigned short*)d_ws;
        unsigned short* Wb  = ihb + IH_ELEMS;
        const int cvt_blocks = (int)((IH_ELEMS + W_ELEMS) / 8 / 256);   // 32768
        cvt_all<<<cvt_blocks, 256, 0, stream>>>(I, H, W1, W2, W3, W4, ihb);
        lstm_gemm_8ph<<<dim3((BATCH / TBM) * (OUT / (TBN / 4))), dim3(512), 0, stream>>>(
            ihb, Wb, C, B1, B2, B3, B4, Outp);
    } else {
        dim3 grid(OUT / FBO, BATCH / FBM);
        lstm_fused_f32<<<grid, 256, 0, stream>>>(I, H, C, W1, B1, W2, B2,
                                                 W3, B3, W4, B4, Outp);
    }
}